// Round 3
// baseline (272.282 us; speedup 1.0000x reference)
//
#include <hip/hip_runtime.h>
#include <math.h>

// ---------------------------------------------------------------------------
// Pipeline v6 — one-level dst bucketing + LDS-accumulate aggregation.
// Evidence from v4 A/B: 8M contended LDS atomics cost only ~5us (not the
// lane-serialized ~55us model). So the full per-node sort (k_sort: scan +
// scatter + 32MB writeback + 32MB re-read) existed only to enable atomic-free
// segment walks whose degree imbalance wastes ~1.7x gather slots anyway.
// v6 deletes k_sort:
//   k_bucket : radix pass 1 (dst>>10) — v3 verbatim, proven.
//   k_deg    : per bucket, histogram dst&1023 (1 LDS atomic/edge);
//              epilogue dinv[g], u[g]=bf16(x*dinv).
//   k_acc1   : per bucket, stream file coalesced (uniform, no imbalance),
//              gather u[src], LDS atomicAdd into acc[dst&1023];
//              epilogue MLP 1->16->2, q packed 2xbf16.
//   k_acc2   : same on q (2 LDS atomics/edge), epilogue +self, *dinv, +b2,
//              log_softmax.
// Plain loads everywhere (round-2 lesson: nt bypasses L1 line reuse on the
// file stream and regresses ~+11us/kernel).
// ---------------------------------------------------------------------------

#define NPB 1024            // nodes per bucket
#define NPB_SHIFT 10
#define NPB_MASK (NPB - 1)
#define MAXB 512            // max buckets
#define P1T 512             // k_bucket threads
#define CHUNK 16384         // edges per k_bucket block
#define SORT_CAP 17408      // per-bucket file capacity (mean 16384 + 8sigma)

__device__ __forceinline__ unsigned short f2bf(float f) {
    unsigned int x = __float_as_uint(f);
    x += 0x7fffu + ((x >> 16) & 1u);            // round-to-nearest-even
    return (unsigned short)(x >> 16);
}
__device__ __forceinline__ float bf2f(unsigned short h) {
    return __uint_as_float((unsigned int)h << 16);
}

// ---------------------------------------------------------------------------
// Phase 1: bucket by dst>>10, coalesced per-wave run write-out. (v3 verbatim)
// ---------------------------------------------------------------------------
__global__ __launch_bounds__(P1T, 4) void k_bucket(
    const int* __restrict__ src, const int* __restrict__ dst,
    unsigned int* __restrict__ file, int* __restrict__ ctr,
    int E, int nbucket, int cap)
{
    __shared__ unsigned int sorted[CHUNK];   // 64 KB
    __shared__ int cnt[MAXB];
    __shared__ int pre[MAXB + 1];
    __shared__ int gb[MAXB];
    __shared__ int rk[MAXB];

    const int t  = threadIdx.x;
    const int e0 = blockIdx.x * CHUNK;
    const int nE = min(CHUNK, E - e0);

    for (int b = t; b < MAXB; b += P1T) { cnt[b] = 0; rk[b] = 0; }
    __syncthreads();

    const bool full = (nE == CHUNK);
    int4 dc[8];

    if (full) {
        const int4* d4 = (const int4*)(dst + e0);
#pragma unroll
        for (int k = 0; k < 8; ++k) dc[k] = d4[t + k * P1T];
#pragma unroll
        for (int k = 0; k < 8; ++k) {
            atomicAdd(&cnt[((unsigned)dc[k].x) >> NPB_SHIFT], 1);
            atomicAdd(&cnt[((unsigned)dc[k].y) >> NPB_SHIFT], 1);
            atomicAdd(&cnt[((unsigned)dc[k].z) >> NPB_SHIFT], 1);
            atomicAdd(&cnt[((unsigned)dc[k].w) >> NPB_SHIFT], 1);
        }
    } else {
        for (int i = t; i < nE; i += P1T)
            atomicAdd(&cnt[((unsigned)dst[e0 + i]) >> NPB_SHIFT], 1);
    }
    __syncthreads();

    int v = (t < nbucket) ? cnt[t] : 0;
    pre[t + 1] = v;
    if (t == 0) pre[0] = 0;
    __syncthreads();
    for (int off = 1; off < P1T; off <<= 1) {
        int add = (t >= off) ? pre[t + 1 - off] : 0;
        __syncthreads();
        pre[t + 1] += add;
        __syncthreads();
    }

    for (int b = t; b < nbucket; b += P1T) {
        int c = cnt[b];
        gb[b] = c ? atomicAdd(&ctr[b], c) : 0;
    }
    __syncthreads();

    if (full) {
        const int4* s4 = (const int4*)(src + e0);
#pragma unroll
        for (int k = 0; k < 8; ++k) {
            int4 s = s4[t + k * P1T];
            int4 d = dc[k];
            {
                int b = ((unsigned)d.x) >> NPB_SHIFT;
                int r = atomicAdd(&rk[b], 1);
                sorted[pre[b] + r] = (((unsigned)s.x) << NPB_SHIFT) | ((unsigned)d.x & NPB_MASK);
            }
            {
                int b = ((unsigned)d.y) >> NPB_SHIFT;
                int r = atomicAdd(&rk[b], 1);
                sorted[pre[b] + r] = (((unsigned)s.y) << NPB_SHIFT) | ((unsigned)d.y & NPB_MASK);
            }
            {
                int b = ((unsigned)d.z) >> NPB_SHIFT;
                int r = atomicAdd(&rk[b], 1);
                sorted[pre[b] + r] = (((unsigned)s.z) << NPB_SHIFT) | ((unsigned)d.z & NPB_MASK);
            }
            {
                int b = ((unsigned)d.w) >> NPB_SHIFT;
                int r = atomicAdd(&rk[b], 1);
                sorted[pre[b] + r] = (((unsigned)s.w) << NPB_SHIFT) | ((unsigned)d.w & NPB_MASK);
            }
        }
    } else {
        for (int i = t; i < nE; i += P1T) {
            int d = dst[e0 + i];
            int b = ((unsigned)d) >> NPB_SHIFT;
            unsigned int w = (((unsigned)src[e0 + i]) << NPB_SHIFT) |
                             ((unsigned)d & NPB_MASK);
            int r = atomicAdd(&rk[b], 1);
            sorted[pre[b] + r] = w;
        }
    }
    __syncthreads();

    {   // per-wave run write-out, clamped to cap
        const int wid  = t >> 6;
        const int lane = t & 63;
        const int nw   = P1T >> 6;
        for (int b = wid; b < nbucket; b += nw) {
            int s0 = pre[b], s1 = pre[b + 1];
            int base = gb[b];
            unsigned int* dp = file + (size_t)b * cap;
            for (int j = s0 + lane; j < s1; j += 64) {
                int idx = base + (j - s0);
                if (idx < cap)
                    __builtin_nontemporal_store(sorted[j], &dp[idx]);
            }
        }
    }
}

// ---------------------------------------------------------------------------
// Phase 2: per-bucket degree histogram (1 LDS atomic/edge, no sort).
// Epilogue: dinv, u = bf16(x*dinv).
// ---------------------------------------------------------------------------
__global__ __launch_bounds__(NPB) void k_deg(
    const unsigned int* __restrict__ file, const int* __restrict__ ctr,
    const float* __restrict__ x, float* __restrict__ dinv,
    unsigned short* __restrict__ u, int N, int cap)
{
    __shared__ int cnt[NPB];

    const int t = threadIdx.x;
    const int b = blockIdx.x;
    const int nb = min(ctr[b], cap);
    const unsigned int* f = file + (size_t)b * cap;

    cnt[t] = 0;
    __syncthreads();

    const int nb4 = nb & ~3;
    for (int i = 4 * t; i < nb4; i += 4 * NPB) {
        uint4 ev = *(const uint4*)(f + i);
        atomicAdd(&cnt[ev.x & NPB_MASK], 1);
        atomicAdd(&cnt[ev.y & NPB_MASK], 1);
        atomicAdd(&cnt[ev.z & NPB_MASK], 1);
        atomicAdd(&cnt[ev.w & NPB_MASK], 1);
    }
    if (t < nb - nb4)
        atomicAdd(&cnt[f[nb4 + t] & NPB_MASK], 1);
    __syncthreads();

    const int g = b * NPB + t;
    if (g < N) {
        float dv = rsqrtf((float)(cnt[t] + 1));   // +1 self-loop
        dinv[g] = dv;
        u[g] = f2bf(x[g] * dv);
    }
}

// ---------------------------------------------------------------------------
// Phase 3: per-bucket accumulate of u[src] into acc[dst&1023] (1 atomic/edge,
// uniform edge-strided loop — no degree imbalance). Epilogue: MLP -> q.
// ---------------------------------------------------------------------------
__global__ __launch_bounds__(NPB) void k_acc1(
    const unsigned int* __restrict__ file, const int* __restrict__ ctr,
    const unsigned short* __restrict__ u, const float* __restrict__ dinv,
    const float* __restrict__ W1, const float* __restrict__ b1,
    const float* __restrict__ W2, unsigned int* __restrict__ q,
    int N, int cap)
{
    __shared__ float acc[NPB];

    const int t = threadIdx.x;
    const int b = blockIdx.x;
    const int nb = min(ctr[b], cap);
    const unsigned int* f = file + (size_t)b * cap;

    acc[t] = 0.f;
    __syncthreads();

    const int nb4 = nb & ~3;
    for (int i = 4 * t; i < nb4; i += 4 * NPB) {
        uint4 ev = *(const uint4*)(f + i);
        float v0 = bf2f(u[ev.x >> NPB_SHIFT]);
        float v1 = bf2f(u[ev.y >> NPB_SHIFT]);
        float v2 = bf2f(u[ev.z >> NPB_SHIFT]);
        float v3 = bf2f(u[ev.w >> NPB_SHIFT]);
        atomicAdd(&acc[ev.x & NPB_MASK], v0);
        atomicAdd(&acc[ev.y & NPB_MASK], v1);
        atomicAdd(&acc[ev.z & NPB_MASK], v2);
        atomicAdd(&acc[ev.w & NPB_MASK], v3);
    }
    if (t < nb - nb4) {
        unsigned int ev = f[nb4 + t];
        atomicAdd(&acc[ev & NPB_MASK], bf2f(u[ev >> NPB_SHIFT]));
    }
    __syncthreads();

    const int g = b * NPB + t;
    if (g < N) {
        float dv = dinv[g];
        float s1v = (acc[t] + bf2f(u[g])) * dv;
        float c0 = 0.f, c1 = 0.f;
#pragma unroll
        for (int k = 0; k < 16; ++k) {
            float h = fmaxf(fmaf(s1v, W1[k], b1[k]), 0.f);
            c0 = fmaf(h, W2[2 * k], c0);
            c1 = fmaf(h, W2[2 * k + 1], c1);
        }
        q[g] = (unsigned int)f2bf(c0 * dv) | ((unsigned int)f2bf(c1 * dv) << 16);
    }
}

// ---------------------------------------------------------------------------
// Phase 4: same walk on q (2 LDS atomics/edge). Epilogue: +self, *dinv, +b2,
// log_softmax.
// ---------------------------------------------------------------------------
__global__ __launch_bounds__(NPB) void k_acc2(
    const unsigned int* __restrict__ file, const int* __restrict__ ctr,
    const unsigned int* __restrict__ q, const float* __restrict__ dinv,
    const float* __restrict__ b2, float2* __restrict__ out,
    int N, int cap)
{
    __shared__ float a0[NPB];
    __shared__ float a1[NPB];

    const int t = threadIdx.x;
    const int b = blockIdx.x;
    const int nb = min(ctr[b], cap);
    const unsigned int* f = file + (size_t)b * cap;

    a0[t] = 0.f;
    a1[t] = 0.f;
    __syncthreads();

    const int nb4 = nb & ~3;
    for (int i = 4 * t; i < nb4; i += 4 * NPB) {
        uint4 ev = *(const uint4*)(f + i);
        unsigned int g0 = q[ev.x >> NPB_SHIFT];
        unsigned int g1 = q[ev.y >> NPB_SHIFT];
        unsigned int g2 = q[ev.z >> NPB_SHIFT];
        unsigned int g3 = q[ev.w >> NPB_SHIFT];
        atomicAdd(&a0[ev.x & NPB_MASK], bf2f((unsigned short)g0));
        atomicAdd(&a1[ev.x & NPB_MASK], bf2f((unsigned short)(g0 >> 16)));
        atomicAdd(&a0[ev.y & NPB_MASK], bf2f((unsigned short)g1));
        atomicAdd(&a1[ev.y & NPB_MASK], bf2f((unsigned short)(g1 >> 16)));
        atomicAdd(&a0[ev.z & NPB_MASK], bf2f((unsigned short)g2));
        atomicAdd(&a1[ev.z & NPB_MASK], bf2f((unsigned short)(g2 >> 16)));
        atomicAdd(&a0[ev.w & NPB_MASK], bf2f((unsigned short)g3));
        atomicAdd(&a1[ev.w & NPB_MASK], bf2f((unsigned short)(g3 >> 16)));
    }
    if (t < nb - nb4) {
        unsigned int ev = f[nb4 + t];
        unsigned int gq = q[ev >> NPB_SHIFT];
        atomicAdd(&a0[ev & NPB_MASK], bf2f((unsigned short)gq));
        atomicAdd(&a1[ev & NPB_MASK], bf2f((unsigned short)(gq >> 16)));
    }
    __syncthreads();

    const int g = b * NPB + t;
    if (g < N) {
        float dv = dinv[g];
        unsigned int qi = q[g];
        float o0 = (a0[t] + bf2f((unsigned short)qi)) * dv + b2[0];
        float o1 = (a1[t] + bf2f((unsigned short)(qi >> 16))) * dv + b2[1];
        float m = fmaxf(o0, o1);
        float l = m + logf(expf(o0 - m) + expf(o1 - m));
        out[g] = make_float2(o0 - l, o1 - l);
    }
}

// ===========================================================================
// Fallback path (direct-atomic, fp32) if workspace/shape doesn't fit.
// ===========================================================================
#define NT 256
__global__ __launch_bounds__(NT) void fb_deg(const int* __restrict__ dst,
                                             int* __restrict__ deg, int E) {
    int e = blockIdx.x * blockDim.x + threadIdx.x;
    if (e < E) atomicAdd(&deg[dst[e]], 1);
}
__global__ __launch_bounds__(NT) void fb_node1(const float* __restrict__ x,
                                               const int* __restrict__ deg,
                                               float* __restrict__ dinv,
                                               float* __restrict__ u, int N) {
    int i = blockIdx.x * blockDim.x + threadIdx.x;
    if (i < N) {
        float dv = rsqrtf((float)(deg[i] + 1));
        dinv[i] = dv;
        u[i] = x[i] * dv;
    }
}
__global__ __launch_bounds__(NT) void fb_edge1(const int* __restrict__ src,
                                               const int* __restrict__ dst,
                                               const float* __restrict__ u,
                                               float* __restrict__ agg1, int E) {
    int e = blockIdx.x * blockDim.x + threadIdx.x;
    if (e < E) atomicAdd(&agg1[dst[e]], u[src[e]]);
}
__global__ __launch_bounds__(NT) void fb_node2(const float* __restrict__ agg1,
                                               const float* __restrict__ u,
                                               const float* __restrict__ dinv,
                                               const float* __restrict__ W1,
                                               const float* __restrict__ b1,
                                               const float* __restrict__ W2,
                                               float2* __restrict__ q, int N) {
    int i = blockIdx.x * blockDim.x + threadIdx.x;
    if (i < N) {
        float dv = dinv[i];
        float s1 = (agg1[i] + u[i]) * dv;
        float c0 = 0.f, c1 = 0.f;
#pragma unroll
        for (int k = 0; k < 16; ++k) {
            float h = fmaxf(fmaf(s1, W1[k], b1[k]), 0.f);
            c0 = fmaf(h, W2[2 * k], c0);
            c1 = fmaf(h, W2[2 * k + 1], c1);
        }
        q[i] = make_float2(c0 * dv, c1 * dv);
    }
}
__global__ __launch_bounds__(NT) void fb_edge2(const int* __restrict__ src,
                                               const int* __restrict__ dst,
                                               const float2* __restrict__ q,
                                               float* __restrict__ agg2, int E) {
    int e = blockIdx.x * blockDim.x + threadIdx.x;
    if (e < E) {
        float2 qq = q[src[e]];
        atomicAdd(&agg2[2 * dst[e]], qq.x);
        atomicAdd(&agg2[2 * dst[e] + 1], qq.y);
    }
}
__global__ __launch_bounds__(NT) void fb_node3(const float* __restrict__ agg2,
                                               const float2* __restrict__ q,
                                               const float* __restrict__ dinv,
                                               const float* __restrict__ b2,
                                               float2* __restrict__ out, int N) {
    int i = blockIdx.x * blockDim.x + threadIdx.x;
    if (i < N) {
        float dv = dinv[i];
        float2 qi = q[i];
        float o0 = (agg2[2 * i] + qi.x) * dv + b2[0];
        float o1 = (agg2[2 * i + 1] + qi.y) * dv + b2[1];
        float m = fmaxf(o0, o1);
        float l = m + logf(expf(o0 - m) + expf(o1 - m));
        out[i] = make_float2(o0 - l, o1 - l);
    }
}

// ===========================================================================
extern "C" void kernel_launch(void* const* d_in, const int* in_sizes, int n_in,
                              void* d_out, int out_size, void* d_ws, size_t ws_size,
                              hipStream_t stream) {
    const float* x  = (const float*)d_in[0];
    const int* ei   = (const int*)d_in[1];
    const float* W1 = (const float*)d_in[2];
    const float* b1 = (const float*)d_in[3];
    const float* W2 = (const float*)d_in[4];
    const float* b2 = (const float*)d_in[5];

    const int N = in_sizes[0];
    const int E = in_sizes[1] / 2;
    const int* src = ei;
    const int* dst = ei + E;

    const int nbucket = (N + NPB - 1) / NPB;
    const int cap = ((E / nbucket + 1024) + 63) & ~63;   // must be <= SORT_CAP

    auto align_up = [](size_t v) { return (v + 255) & ~(size_t)255; };
    size_t off_ctr   = 0;
    size_t off_file  = align_up((size_t)MAXB * sizeof(int));
    size_t off_dinv  = align_up(off_file + (size_t)nbucket * SORT_CAP * sizeof(unsigned int));
    size_t off_u     = align_up(off_dinv + (size_t)N * sizeof(float));
    size_t off_q     = align_up(off_u + (size_t)N * sizeof(unsigned short));
    size_t needed    = off_q + (size_t)N * sizeof(unsigned int);

    char* ws = (char*)d_ws;

    if (nbucket <= MAXB && cap <= SORT_CAP && needed <= ws_size) {
        int*            ctr   = (int*)(ws + off_ctr);
        unsigned int*   file  = (unsigned int*)(ws + off_file);
        float*          dinv  = (float*)(ws + off_dinv);
        unsigned short* u     = (unsigned short*)(ws + off_u);
        unsigned int*   q     = (unsigned int*)(ws + off_q);

        (void)hipMemsetAsync(ctr, 0, (size_t)MAXB * sizeof(int), stream);

        const int p1Blocks = (E + CHUNK - 1) / CHUNK;
        k_bucket<<<p1Blocks, P1T, 0, stream>>>(src, dst, file, ctr, E, nbucket, SORT_CAP);
        k_deg   <<<nbucket, NPB, 0, stream>>>(file, ctr, x, dinv, u, N, SORT_CAP);
        k_acc1  <<<nbucket, NPB, 0, stream>>>(file, ctr, u, dinv, W1, b1, W2, q, N, SORT_CAP);
        k_acc2  <<<nbucket, NPB, 0, stream>>>(file, ctr, q, dinv, b2, (float2*)d_out, N, SORT_CAP);
    } else {
        int*    deg  = (int*)   (ws);
        float*  agg1 = (float*) (ws + (size_t)4 * N);
        float*  agg2 = (float*) (ws + (size_t)8 * N);
        float*  dinv = (float*) (ws + (size_t)16 * N);
        float*  u    = (float*) (ws + (size_t)20 * N);
        float2* q    = (float2*)(ws + (size_t)24 * N);
        (void)hipMemsetAsync(ws, 0, (size_t)16 * N, stream);
        const int nodeBlocks = (N + NT - 1) / NT;
        const int edgeBlocks = (E + NT - 1) / NT;
        fb_deg  <<<edgeBlocks, NT, 0, stream>>>(dst, deg, E);
        fb_node1<<<nodeBlocks, NT, 0, stream>>>(x, deg, dinv, u, N);
        fb_edge1<<<edgeBlocks, NT, 0, stream>>>(src, dst, u, agg1, E);
        fb_node2<<<nodeBlocks, NT, 0, stream>>>(agg1, u, dinv, W1, b1, W2, q, N);
        fb_edge2<<<edgeBlocks, NT, 0, stream>>>(src, dst, q, agg2, E);
        fb_node3<<<nodeBlocks, NT, 0, stream>>>(agg2, q, dinv, b2, (float2*)d_out, N);
    }
}